// Round 3
// baseline (2887.473 us; speedup 1.0000x reference)
//
#include <hip/hip_runtime.h>
#include <hip/hip_bf16.h>
#include <math.h>

// ---- problem constants ----
#define BB 8
#define TT 90
#define HH 290
#define WWI 180
#define PSZ 10
#define NHPc 29
#define NWPc 18
#define NPc 522
#define PDc 100
#define NVc 94
#define KKc 24
#define LLc 2160
#define LPc 2176          // padded L (multiple of 32/64)
#define DDc 256
#define NHEADc 8
#define DHc 32
#define NLc 6
#define DFFc 1024
#define MTOT (BB*LLc)     // 17280

using f32x4 = __attribute__((ext_vector_type(4))) float;
using s16x8 = __attribute__((ext_vector_type(8))) short;
using s16x4 = __attribute__((ext_vector_type(4))) short;

__device__ __forceinline__ short f2bf(float f) {
  union { __hip_bfloat16 h; short s; } u;
  u.h = __float2bfloat16(f);
  return u.s;
}

// ---------------- fp32 -> bf16 weight conversion ----------------
__global__ void cvt_bf16_kernel(const float* __restrict__ src, short* __restrict__ dst, int n) {
  int i = blockIdx.x * 256 + threadIdx.x;
  if (i < n) dst[i] = f2bf(src[i]);
}

// ---------------- sinusoidal PE table (fp32) ----------------
__global__ void pe_kernel(float* __restrict__ pe) {
  int idx = blockIdx.x * 256 + threadIdx.x;
  if (idx >= TT * 128) return;
  int t = idx / 128, i = idx % 128;
  float div = expf((2.0f * i) * (-9.210340371976184f / 256.0f)); // -ln(10000)/256
  float ang = (float)t * div;
  pe[t * DDc + 2 * i]     = sinf(ang);
  pe[t * DDc + 2 * i + 1] = cosf(ang);
}

// ---------------- visible-token ordering: p_idx[b*L + t*K + j] = v ----------------
__global__ void order_kernel(const unsigned char* __restrict__ pm8,
                             const int* __restrict__ vidx, int* __restrict__ pidx) {
  int gw = (blockIdx.x * blockDim.x + threadIdx.x) >> 6;
  int lane = threadIdx.x & 63;
  if (gw >= BB * TT) return;
  size_t base = (size_t)gw * NPc;  // gw = b*TT + t
  int v0 = lane, v1 = 64 + lane;
  bool vis0 = (pm8[base + vidx[v0]] == 0);
  bool vis1 = (v1 < NVc) && (pm8[base + vidx[v1]] == 0);
  unsigned long long b0 = __ballot(vis0), b1 = __ballot(vis1);
  if (__popcll(b0) + __popcll(b1) != KKc) {   // mask was stored as int32
    const int* pm32 = (const int*)pm8;
    vis0 = (pm32[base + vidx[v0]] == 0);
    vis1 = (v1 < NVc) && (pm32[base + vidx[v1]] == 0);
    b0 = __ballot(vis0); b1 = __ballot(vis1);
  }
  int* outp = pidx + gw * KKc;   // b*L + t*K == gw*K
  unsigned long long lt = (1ull << lane) - 1ull;
  if (vis0) outp[__popcll(b0 & lt)] = v0;
  if (vis1) outp[__popcll(b0) + __popcll(b1 & lt)] = v1;
}

// ---------------- patch gather + embed + pos enc ----------------
__global__ __launch_bounds__(256) void embed_kernel(
    const float* __restrict__ ximg, const int* __restrict__ vidx,
    const int* __restrict__ pidx, const float* __restrict__ pew,
    const float* __restrict__ peb, const float* __restrict__ sp,
    const float* __restrict__ petab, float* __restrict__ x, short* __restrict__ xb) {
  __shared__ float px[4][PDc];
  int m0 = blockIdx.x * 4;
  for (int idx = threadIdx.x; idx < 4 * PDc; idx += 256) {
    int tok = idx / PDc, k = idx % PDc;
    int m = m0 + tok;
    int b = m / LLc, l = m % LLc;
    int t = l / KKc;
    int v = pidx[m];
    int np_ = vidx[v];
    int hp = np_ / NWPc, wp = np_ % NWPc;
    int r = k / PSZ, c = k % PSZ;
    px[tok][k] = ximg[(((size_t)b * TT + t) * HH + hp * PSZ + r) * WWI + wp * PSZ + c];
  }
  __syncthreads();
  int d = threadIdx.x;
  float a0 = 0.f, a1 = 0.f, a2 = 0.f, a3 = 0.f;
  const float* wrow = pew + (size_t)d * PDc;
#pragma unroll 4
  for (int k = 0; k < PDc; k++) {
    float w = wrow[k];
    a0 += w * px[0][k]; a1 += w * px[1][k]; a2 += w * px[2][k]; a3 += w * px[3][k];
  }
  float accs[4] = {a0, a1, a2, a3};
#pragma unroll
  for (int tok = 0; tok < 4; tok++) {
    int m = m0 + tok;
    int l = m % LLc; int t = l / KKc;
    int v = pidx[m];
    float val = accs[tok] + peb[d] + sp[(size_t)v * DDc + d] + petab[(size_t)t * DDc + d];
    x[(size_t)m * DDc + d] = val;
    xb[(size_t)m * DDc + d] = f2bf(val);
  }
}

// ---------------- generic bf16 MFMA GEMM: C[m,n] = sum_k A[m,k]*W[n,k] + bias[n] ----------------
#define GM_QKV 0
#define GM_F32 1
#define GM_RELU 2

template <int MODE>
__global__ __launch_bounds__(256) void gemm_bt(
    const short* __restrict__ A, int lda,
    const short* __restrict__ W, int ldw,
    const float* __restrict__ bias,
    void* __restrict__ outp, int N, int K,
    short* __restrict__ vT, float qscale) {
  __shared__ short As[64][40];
  __shared__ short Ws[64][40];
  int tid = threadIdx.x;
  int m0 = blockIdx.x * 64;
  int n0 = blockIdx.y * 64;
  int wave = tid >> 6, lane = tid & 63;
  int wr = (wave >> 1) * 32, wc = (wave & 1) * 32;
  int g = lane >> 4, c = lane & 15;
  f32x4 acc[2][2];
#pragma unroll
  for (int i = 0; i < 2; i++)
#pragma unroll
    for (int j = 0; j < 2; j++) { acc[i][j][0] = 0.f; acc[i][j][1] = 0.f; acc[i][j][2] = 0.f; acc[i][j][3] = 0.f; }
  int lrow = tid >> 2, lcg = (tid & 3) * 8;
  const short* aptr = A + (size_t)(m0 + lrow) * lda + lcg;
  const short* wptr = W + (size_t)(n0 + lrow) * ldw + lcg;
  for (int k0 = 0; k0 < K; k0 += 32) {
    *(s16x8*)&As[lrow][lcg] = *(const s16x8*)(aptr + k0);
    *(s16x8*)&Ws[lrow][lcg] = *(const s16x8*)(wptr + k0);
    __syncthreads();
    s16x8 va0 = *(const s16x8*)&As[wr + c][g * 8];
    s16x8 va1 = *(const s16x8*)&As[wr + 16 + c][g * 8];
    s16x8 vb0 = *(const s16x8*)&Ws[wc + c][g * 8];
    s16x8 vb1 = *(const s16x8*)&Ws[wc + 16 + c][g * 8];
    acc[0][0] = __builtin_amdgcn_mfma_f32_16x16x32_bf16(va0, vb0, acc[0][0], 0, 0, 0);
    acc[0][1] = __builtin_amdgcn_mfma_f32_16x16x32_bf16(va0, vb1, acc[0][1], 0, 0, 0);
    acc[1][0] = __builtin_amdgcn_mfma_f32_16x16x32_bf16(va1, vb0, acc[1][0], 0, 0, 0);
    acc[1][1] = __builtin_amdgcn_mfma_f32_16x16x32_bf16(va1, vb1, acc[1][1], 0, 0, 0);
    __syncthreads();
  }
#pragma unroll
  for (int i = 0; i < 2; i++)
#pragma unroll
    for (int j = 0; j < 2; j++) {
      int mbase = m0 + wr + i * 16 + g * 4;
      int n = n0 + wc + j * 16 + c;
      float bv = bias[n];
#pragma unroll
      for (int r = 0; r < 4; r++) {
        int m = mbase + r;
        float val = acc[i][j][r] + bv;
        if (MODE == GM_QKV) {
          int b = m / LLc, l = m % LLc;
          if (n < 512) {
            if (n < 256) val *= qscale;   // fold softmax scale * log2e into q
            ((short*)outp)[((size_t)b * LPc + l) * 768 + n] = f2bf(val);
          } else {
            // v stored transposed: vT[(b*256 + d)*LP + l]
            vT[((size_t)b * DDc + (n - 512)) * LPc + l] = f2bf(val);
          }
        } else if (MODE == GM_F32) {
          ((float*)outp)[(size_t)m * N + n] = val;
        } else {  // GM_RELU -> bf16
          ((short*)outp)[(size_t)m * N + n] = f2bf(val > 0.f ? val : 0.f);
        }
      }
    }
}

// ---------------- flash attention v2: fixed-shift softmax, sum via ones-MFMA ----------------
// Softmax is shift-invariant; scores (q.k * scale * log2e) are bounded |s| << 127,
// so exp2(s) cannot overflow f32 and the online max/rescale machinery is dead weight.
// Row-sum comes from one extra MFMA against an all-ones B fragment (sums the exact
// bf16 P used in PV). No cross-lane shuffles remain.
__global__ __launch_bounds__(256) void flash_kernel(
    const short* __restrict__ qkv, const short* __restrict__ vT,
    short* __restrict__ attnout) {
  __shared__ short plds[4][16 * 40];   // per-wave P transpose buffer (stride 40 bf16)
  int wave = threadIdx.x >> 6, lane = threadIdx.x & 63;
  int g = lane >> 4, c = lane & 15;
  int bh = blockIdx.y;
  int b = bh >> 3, h = bh & 7;
  int q0 = blockIdx.x * 64 + wave * 16;

  const short* qptr = qkv + ((size_t)b * LPc + q0 + c) * 768 + h * 32 + g * 8;
  s16x8 qfrag = *(const s16x8*)qptr;
  const short* kbase = qkv + (size_t)b * LPc * 768 + 256 + h * 32 + g * 8;
  const short* vbase = vT + ((size_t)b * DDc + h * 32) * LPc;
  short* pw = &plds[wave][0];

  f32x4 o0, o1, osum;
  o0[0]=o0[1]=o0[2]=o0[3]=0.f; o1[0]=o1[1]=o1[2]=o1[3]=0.f;
  osum[0]=osum[1]=osum[2]=osum[3]=0.f;
  f32x4 zero4; zero4[0]=zero4[1]=zero4[2]=zero4[3]=0.f;
  s16x8 ones;
#pragma unroll
  for (int j = 0; j < 8; j++) ones[j] = (short)0x3F80;  // bf16 1.0

  for (int kt = 0; kt < 68; kt++) {
    int key0 = kt * 32;
    s16x8 kf0 = *(const s16x8*)(kbase + (size_t)(key0 + c) * 768);
    s16x8 kf1 = *(const s16x8*)(kbase + (size_t)(key0 + 16 + c) * 768);
    f32x4 s0 = __builtin_amdgcn_mfma_f32_16x16x32_bf16(qfrag, kf0, zero4, 0, 0, 0);
    f32x4 s1 = __builtin_amdgcn_mfma_f32_16x16x32_bf16(qfrag, kf1, zero4, 0, 0, 0);
    if (kt == 67) {
      // keys 2160..2175 are padding (possibly poison -> NaN): kill by assignment
      s1[0] = s1[1] = s1[2] = s1[3] = -1e30f;
    }
#pragma unroll
    for (int i = 0; i < 4; i++) {
      pw[(g * 4 + i) * 40 + c]      = f2bf(exp2f(s0[i]));
      pw[(g * 4 + i) * 40 + 16 + c] = f2bf(exp2f(s1[i]));
    }
    asm volatile("s_waitcnt lgkmcnt(0)" ::: "memory");
    s16x8 pa = *(const s16x8*)(pw + c * 40 + g * 8);
    const short* vp = vbase + (size_t)c * LPc + key0 + g * 8;
    s16x8 vf0 = *(const s16x8*)vp;
    s16x8 vf1 = *(const s16x8*)(vp + 16 * LPc);
    o0   = __builtin_amdgcn_mfma_f32_16x16x32_bf16(pa, vf0, o0, 0, 0, 0);
    o1   = __builtin_amdgcn_mfma_f32_16x16x32_bf16(pa, vf1, o1, 0, 0, 0);
    osum = __builtin_amdgcn_mfma_f32_16x16x32_bf16(pa, ones, osum, 0, 0, 0);
  }
#pragma unroll
  for (int i = 0; i < 4; i++) {
    int l = q0 + g * 4 + i;
    if (l < LLc) {
      float inv = 1.0f / osum[i];
      attnout[((size_t)b * LLc + l) * DDc + h * 32 + c]      = f2bf(o0[i] * inv);
      attnout[((size_t)b * LLc + l) * DDc + h * 32 + 16 + c] = f2bf(o1[i] * inv);
    }
  }
}

// ---------------- residual + layernorm (one wave per row of 256) ----------------
__global__ __launch_bounds__(256) void ln_kernel(
    const float* __restrict__ xin, const float* __restrict__ res,
    const float* __restrict__ gs, const float* __restrict__ gb,
    float* __restrict__ xout, short* __restrict__ xbout, int rows) {
  int wid = (blockIdx.x * 256 + threadIdx.x) >> 6;
  int lane = threadIdx.x & 63;
  if (wid >= rows) return;
  int dbase = lane * 4;
  float4 v = *(const float4*)(xin + (size_t)wid * DDc + dbase);
  if (res) {
    float4 r = *(const float4*)(res + (size_t)wid * DDc + dbase);
    v.x += r.x; v.y += r.y; v.z += r.z; v.w += r.w;
  }
  float s = v.x + v.y + v.z + v.w;
#pragma unroll
  for (int d = 1; d < 64; d <<= 1) s += __shfl_xor(s, d);
  float mean = s * (1.0f / 256.0f);
  float dx = v.x - mean, dy = v.y - mean, dz = v.z - mean, dw = v.w - mean;
  float sq = dx * dx + dy * dy + dz * dz + dw * dw;
#pragma unroll
  for (int d = 1; d < 64; d <<= 1) sq += __shfl_xor(sq, d);
  float rstd = rsqrtf(sq * (1.0f / 256.0f) + 1e-5f);
  float4 sg = *(const float4*)(gs + dbase);
  float4 bg = *(const float4*)(gb + dbase);
  float o0 = dx * rstd * sg.x + bg.x;
  float o1 = dy * rstd * sg.y + bg.y;
  float o2 = dz * rstd * sg.z + bg.z;
  float o3 = dw * rstd * sg.w + bg.w;
  float4 ov; ov.x = o0; ov.y = o1; ov.z = o2; ov.w = o3;
  *(float4*)(xout + (size_t)wid * DDc + dbase) = ov;
  if (xbout) {
    s16x4 pb;
    pb[0] = f2bf(o0); pb[1] = f2bf(o1); pb[2] = f2bf(o2); pb[3] = f2bf(o3);
    *(s16x4*)(xbout + (size_t)wid * DDc + dbase) = pb;
  }
}

// ---------------- launch ----------------
extern "C" void kernel_launch(void* const* d_in, const int* in_sizes, int n_in,
                              void* d_out, int out_size, void* d_ws, size_t ws_size,
                              hipStream_t stream) {
  const float* x_img = (const float*)d_in[0];
  const unsigned char* pmask = (const unsigned char*)d_in[1];
  const int* vidx = (const int*)d_in[2];
  const float* pew = (const float*)d_in[3];
  const float* peb = (const float*)d_in[4];
  const float* sp = (const float*)d_in[5];
  const float* Wqkv = (const float*)d_in[6];
  const float* bqkv = (const float*)d_in[7];
  const float* Wo = (const float*)d_in[8];
  const float* bo = (const float*)d_in[9];
  const float* ln1s = (const float*)d_in[10];
  const float* ln1b = (const float*)d_in[11];
  const float* W1 = (const float*)d_in[12];
  const float* b1 = (const float*)d_in[13];
  const float* W2 = (const float*)d_in[14];
  const float* b2 = (const float*)d_in[15];
  const float* ln2s = (const float*)d_in[16];
  const float* ln2b = (const float*)d_in[17];
  const float* nfs = (const float*)d_in[18];
  const float* nfb = (const float*)d_in[19];

  char* ws = (char*)d_ws;
  size_t o_wq = 0;
  size_t o_wo = o_wq + (size_t)NLc * 768 * DDc * 2;
  size_t o_w1 = o_wo + (size_t)NLc * DDc * DDc * 2;
  size_t o_w2 = o_w1 + (size_t)NLc * DFFc * DDc * 2;
  size_t o_pe = o_w2 + (size_t)NLc * DFFc * DDc * 2;
  size_t o_pi = o_pe + (size_t)TT * DDc * 4;
  size_t o_x  = o_pi + (size_t)MTOT * 4;
  size_t o_xb = o_x  + (size_t)MTOT * DDc * 4;
  size_t o_qk = o_xb + (size_t)MTOT * DDc * 2;
  size_t o_vt = o_qk + (size_t)BB * LPc * 768 * 2;
  size_t o_at = o_vt + (size_t)BB * DDc * LPc * 2;
  size_t o_h  = o_at + (size_t)MTOT * DDc * 2;
  size_t o_ob = o_qk;  // obuf aliases qkv region (free at that point)

  short* wqb = (short*)(ws + o_wq);
  short* wob = (short*)(ws + o_wo);
  short* w1b = (short*)(ws + o_w1);
  short* w2b = (short*)(ws + o_w2);
  float* petab = (float*)(ws + o_pe);
  int* pidx = (int*)(ws + o_pi);
  float* xbuf = (float*)(ws + o_x);
  short* xb = (short*)(ws + o_xb);
  short* qkvb = (short*)(ws + o_qk);
  short* vtb = (short*)(ws + o_vt);
  short* atb = (short*)(ws + o_at);
  short* hb = (short*)(ws + o_h);
  float* obuf = (float*)(ws + o_ob);

  const float qscale = 0.17677669529663687f * 1.4426950408889634f; // 1/sqrt(32) * log2(e)

  {
    int n;
    n = NLc * 768 * DDc;  cvt_bf16_kernel<<<(n + 255) / 256, 256, 0, stream>>>(Wqkv, wqb, n);
    n = NLc * DDc * DDc;  cvt_bf16_kernel<<<(n + 255) / 256, 256, 0, stream>>>(Wo, wob, n);
    n = NLc * DFFc * DDc; cvt_bf16_kernel<<<(n + 255) / 256, 256, 0, stream>>>(W1, w1b, n);
    n = NLc * DFFc * DDc; cvt_bf16_kernel<<<(n + 255) / 256, 256, 0, stream>>>(W2, w2b, n);
  }
  pe_kernel<<<(TT * 128 + 255) / 256, 256, 0, stream>>>(petab);
  order_kernel<<<(BB * TT + 3) / 4, 256, 0, stream>>>(pmask, vidx, pidx);
  embed_kernel<<<MTOT / 4, 256, 0, stream>>>(x_img, vidx, pidx, pew, peb, sp, petab, xbuf, xb);

  for (int i = 0; i < NLc; i++) {
    gemm_bt<GM_QKV><<<dim3(MTOT / 64, 768 / 64), 256, 0, stream>>>(
        xb, DDc, wqb + (size_t)i * 768 * DDc, DDc, bqkv + i * 768,
        qkvb, 768, DDc, vtb, qscale);
    flash_kernel<<<dim3((LLc + 63) / 64, BB * NHEADc), 256, 0, stream>>>(qkvb, vtb, atb);
    gemm_bt<GM_F32><<<dim3(MTOT / 64, DDc / 64), 256, 0, stream>>>(
        atb, DDc, wob + (size_t)i * DDc * DDc, DDc, bo + i * DDc,
        obuf, DDc, DDc, nullptr, 0.f);
    ln_kernel<<<MTOT / 4, 256, 0, stream>>>(xbuf, obuf, ln1s + i * DDc, ln1b + i * DDc, xbuf, xb, MTOT);
    gemm_bt<GM_RELU><<<dim3(MTOT / 64, DFFc / 64), 256, 0, stream>>>(
        xb, DDc, w1b + (size_t)i * DFFc * DDc, DDc, b1 + i * DFFc,
        hb, DFFc, DDc, nullptr, 0.f);
    gemm_bt<GM_F32><<<dim3(MTOT / 64, DDc / 64), 256, 0, stream>>>(
        hb, DFFc, w2b + (size_t)i * DFFc * DDc, DFFc, b2 + i * DDc,
        obuf, DDc, DFFc, nullptr, 0.f);
    ln_kernel<<<MTOT / 4, 256, 0, stream>>>(xbuf, obuf, ln2s + i * DDc, ln2b + i * DDc, xbuf, xb, MTOT);
  }
  ln_kernel<<<MTOT / 4, 256, 0, stream>>>(xbuf, nullptr, nfs, nfb, (float*)d_out, nullptr, MTOT);
}

// Round 4
// 2744.617 us; speedup vs baseline: 1.0520x; 1.0520x over previous
//
#include <hip/hip_runtime.h>
#include <hip/hip_bf16.h>
#include <math.h>

// ---- problem constants ----
#define BB 8
#define TT 90
#define HH 290
#define WWI 180
#define PSZ 10
#define NHPc 29
#define NWPc 18
#define NPc 522
#define PDc 100
#define NVc 94
#define KKc 24
#define LLc 2160
#define LPc 2176          // padded L (multiple of 32/64)
#define DDc 256
#define NHEADc 8
#define DHc 32
#define NLc 6
#define DFFc 1024
#define MTOT (BB*LLc)     // 17280

using f32x4 = __attribute__((ext_vector_type(4))) float;
using s16x8 = __attribute__((ext_vector_type(8))) short;
using s16x4 = __attribute__((ext_vector_type(4))) short;

__device__ __forceinline__ short f2bf(float f) {
  union { __hip_bfloat16 h; short s; } u;
  u.h = __float2bfloat16(f);
  return u.s;
}

// ---------------- fp32 -> bf16 weight conversion ----------------
__global__ void cvt_bf16_kernel(const float* __restrict__ src, short* __restrict__ dst, int n) {
  int i = blockIdx.x * 256 + threadIdx.x;
  if (i < n) dst[i] = f2bf(src[i]);
}

// ---------------- sinusoidal PE table (fp32) ----------------
__global__ void pe_kernel(float* __restrict__ pe) {
  int idx = blockIdx.x * 256 + threadIdx.x;
  if (idx >= TT * 128) return;
  int t = idx / 128, i = idx % 128;
  float div = expf((2.0f * i) * (-9.210340371976184f / 256.0f)); // -ln(10000)/256
  float ang = (float)t * div;
  pe[t * DDc + 2 * i]     = sinf(ang);
  pe[t * DDc + 2 * i + 1] = cosf(ang);
}

// ---------------- visible-token ordering: p_idx[b*L + t*K + j] = v ----------------
__global__ void order_kernel(const unsigned char* __restrict__ pm8,
                             const int* __restrict__ vidx, int* __restrict__ pidx) {
  int gw = (blockIdx.x * blockDim.x + threadIdx.x) >> 6;
  int lane = threadIdx.x & 63;
  if (gw >= BB * TT) return;
  size_t base = (size_t)gw * NPc;  // gw = b*TT + t
  int v0 = lane, v1 = 64 + lane;
  bool vis0 = (pm8[base + vidx[v0]] == 0);
  bool vis1 = (v1 < NVc) && (pm8[base + vidx[v1]] == 0);
  unsigned long long b0 = __ballot(vis0), b1 = __ballot(vis1);
  if (__popcll(b0) + __popcll(b1) != KKc) {   // mask was stored as int32
    const int* pm32 = (const int*)pm8;
    vis0 = (pm32[base + vidx[v0]] == 0);
    vis1 = (v1 < NVc) && (pm32[base + vidx[v1]] == 0);
    b0 = __ballot(vis0); b1 = __ballot(vis1);
  }
  int* outp = pidx + gw * KKc;   // b*L + t*K == gw*K
  unsigned long long lt = (1ull << lane) - 1ull;
  if (vis0) outp[__popcll(b0 & lt)] = v0;
  if (vis1) outp[__popcll(b0) + __popcll(b1 & lt)] = v1;
}

// ---------------- patch gather + embed + pos enc ----------------
__global__ __launch_bounds__(256) void embed_kernel(
    const float* __restrict__ ximg, const int* __restrict__ vidx,
    const int* __restrict__ pidx, const float* __restrict__ pew,
    const float* __restrict__ peb, const float* __restrict__ sp,
    const float* __restrict__ petab, float* __restrict__ x, short* __restrict__ xb) {
  __shared__ float px[4][PDc];
  int m0 = blockIdx.x * 4;
  for (int idx = threadIdx.x; idx < 4 * PDc; idx += 256) {
    int tok = idx / PDc, k = idx % PDc;
    int m = m0 + tok;
    int b = m / LLc, l = m % LLc;
    int t = l / KKc;
    int v = pidx[m];
    int np_ = vidx[v];
    int hp = np_ / NWPc, wp = np_ % NWPc;
    int r = k / PSZ, c = k % PSZ;
    px[tok][k] = ximg[(((size_t)b * TT + t) * HH + hp * PSZ + r) * WWI + wp * PSZ + c];
  }
  __syncthreads();
  int d = threadIdx.x;
  float a0 = 0.f, a1 = 0.f, a2 = 0.f, a3 = 0.f;
  const float* wrow = pew + (size_t)d * PDc;
#pragma unroll 4
  for (int k = 0; k < PDc; k++) {
    float w = wrow[k];
    a0 += w * px[0][k]; a1 += w * px[1][k]; a2 += w * px[2][k]; a3 += w * px[3][k];
  }
  float accs[4] = {a0, a1, a2, a3};
#pragma unroll
  for (int tok = 0; tok < 4; tok++) {
    int m = m0 + tok;
    int l = m % LLc; int t = l / KKc;
    int v = pidx[m];
    float val = accs[tok] + peb[d] + sp[(size_t)v * DDc + d] + petab[(size_t)t * DDc + d];
    x[(size_t)m * DDc + d] = val;
    xb[(size_t)m * DDc + d] = f2bf(val);
  }
}

// ---------------- generic bf16 MFMA GEMM: C[m,n] = sum_k A[m,k]*W[n,k] + bias[n] ----------------
#define GM_QKV 0
#define GM_F32 1
#define GM_RELU 2

template <int MODE>
__global__ __launch_bounds__(256) void gemm_bt(
    const short* __restrict__ A, int lda,
    const short* __restrict__ W, int ldw,
    const float* __restrict__ bias,
    void* __restrict__ outp, int N, int K,
    short* __restrict__ vT, float qscale) {
  __shared__ short As[64][40];
  __shared__ short Ws[64][40];
  int tid = threadIdx.x;
  int m0 = blockIdx.x * 64;
  int n0 = blockIdx.y * 64;
  int wave = tid >> 6, lane = tid & 63;
  int wr = (wave >> 1) * 32, wc = (wave & 1) * 32;
  int g = lane >> 4, c = lane & 15;
  f32x4 acc[2][2];
#pragma unroll
  for (int i = 0; i < 2; i++)
#pragma unroll
    for (int j = 0; j < 2; j++) { acc[i][j][0] = 0.f; acc[i][j][1] = 0.f; acc[i][j][2] = 0.f; acc[i][j][3] = 0.f; }
  int lrow = tid >> 2, lcg = (tid & 3) * 8;
  const short* aptr = A + (size_t)(m0 + lrow) * lda + lcg;
  const short* wptr = W + (size_t)(n0 + lrow) * ldw + lcg;
  for (int k0 = 0; k0 < K; k0 += 32) {
    *(s16x8*)&As[lrow][lcg] = *(const s16x8*)(aptr + k0);
    *(s16x8*)&Ws[lrow][lcg] = *(const s16x8*)(wptr + k0);
    __syncthreads();
    s16x8 va0 = *(const s16x8*)&As[wr + c][g * 8];
    s16x8 va1 = *(const s16x8*)&As[wr + 16 + c][g * 8];
    s16x8 vb0 = *(const s16x8*)&Ws[wc + c][g * 8];
    s16x8 vb1 = *(const s16x8*)&Ws[wc + 16 + c][g * 8];
    acc[0][0] = __builtin_amdgcn_mfma_f32_16x16x32_bf16(va0, vb0, acc[0][0], 0, 0, 0);
    acc[0][1] = __builtin_amdgcn_mfma_f32_16x16x32_bf16(va0, vb1, acc[0][1], 0, 0, 0);
    acc[1][0] = __builtin_amdgcn_mfma_f32_16x16x32_bf16(va1, vb0, acc[1][0], 0, 0, 0);
    acc[1][1] = __builtin_amdgcn_mfma_f32_16x16x32_bf16(va1, vb1, acc[1][1], 0, 0, 0);
    __syncthreads();
  }
#pragma unroll
  for (int i = 0; i < 2; i++)
#pragma unroll
    for (int j = 0; j < 2; j++) {
      int mbase = m0 + wr + i * 16 + g * 4;
      int n = n0 + wc + j * 16 + c;
      float bv = bias[n];
#pragma unroll
      for (int r = 0; r < 4; r++) {
        int m = mbase + r;
        float val = acc[i][j][r] + bv;
        if (MODE == GM_QKV) {
          int b = m / LLc, l = m % LLc;
          if (n < 512) {
            if (n < 256) val *= qscale;   // fold softmax scale * log2e into q
            ((short*)outp)[((size_t)b * LPc + l) * 768 + n] = f2bf(val);
          } else {
            // v stored transposed: vT[(b*256 + d)*LP + l]
            vT[((size_t)b * DDc + (n - 512)) * LPc + l] = f2bf(val);
          }
        } else if (MODE == GM_F32) {
          ((float*)outp)[(size_t)m * N + n] = val;
        } else {  // GM_RELU -> bf16
          ((short*)outp)[(size_t)m * N + n] = f2bf(val > 0.f ? val : 0.f);
        }
      }
    }
}

// ---------------- flash attention v3: fixed-shift softmax + distance-2 prefetch ----------------
// Latency-bound chain fix (r3 post-mortem): issue K/V global loads for tile kt+2
// at the top of tile kt's body into named register sets (no runtime-indexed arrays),
// compute on snapshots. Loads get ~2 iterations in flight; V-loads leave the
// critical path. Softmax: fixed shift (scores bounded far below exp2 overflow),
// row-sum via ones-MFMA.
__device__ __forceinline__ void flash_body(
    int kt, const short* kbase, const short* vbase_cg, short* pw,
    const s16x8& qfrag, const s16x8& ones,
    s16x8& K0, s16x8& K1, s16x8& V0, s16x8& V1,
    f32x4& o0, f32x4& o1, f32x4& osum, int g, int c) {
  // snapshot current tile's operands
  s16x8 ck0 = K0, ck1 = K1, cv0 = V0, cv1 = V1;
  // prefetch tile kt+2 (clamped to row 0 when past the end; loaded-not-used)
  int nk = kt * 32 + 64;
  if (nk >= LPc) nk = 0;
  K0 = *(const s16x8*)(kbase + (size_t)(nk + c) * 768);
  K1 = *(const s16x8*)(kbase + (size_t)(nk + 16 + c) * 768);
  V0 = *(const s16x8*)(vbase_cg + nk);
  V1 = *(const s16x8*)(vbase_cg + nk + 16 * LPc);
  // compute on snapshot
  f32x4 zero4; zero4[0] = zero4[1] = zero4[2] = zero4[3] = 0.f;
  f32x4 s0 = __builtin_amdgcn_mfma_f32_16x16x32_bf16(qfrag, ck0, zero4, 0, 0, 0);
  f32x4 s1 = __builtin_amdgcn_mfma_f32_16x16x32_bf16(qfrag, ck1, zero4, 0, 0, 0);
  if (kt == 67) {
    // keys 2160..2175 are padding (possibly poison -> NaN): kill by assignment
    s1[0] = s1[1] = s1[2] = s1[3] = -1e30f;
  }
#pragma unroll
  for (int i = 0; i < 4; i++) {
    pw[(g * 4 + i) * 40 + c]      = f2bf(exp2f(s0[i]));
    pw[(g * 4 + i) * 40 + 16 + c] = f2bf(exp2f(s1[i]));
  }
  asm volatile("s_waitcnt lgkmcnt(0)" ::: "memory");
  s16x8 pa = *(const s16x8*)(pw + c * 40 + g * 8);
  o0   = __builtin_amdgcn_mfma_f32_16x16x32_bf16(pa, cv0, o0, 0, 0, 0);
  o1   = __builtin_amdgcn_mfma_f32_16x16x32_bf16(pa, cv1, o1, 0, 0, 0);
  osum = __builtin_amdgcn_mfma_f32_16x16x32_bf16(pa, ones, osum, 0, 0, 0);
}

__global__ __launch_bounds__(256) void flash_kernel(
    const short* __restrict__ qkv, const short* __restrict__ vT,
    short* __restrict__ attnout) {
  __shared__ short plds[4][16 * 40];   // per-wave P transpose buffer (stride 40 bf16)
  int wave = threadIdx.x >> 6, lane = threadIdx.x & 63;
  int g = lane >> 4, c = lane & 15;
  int bh = blockIdx.y;
  int b = bh >> 3, h = bh & 7;
  int q0 = blockIdx.x * 64 + wave * 16;

  const short* qptr = qkv + ((size_t)b * LPc + q0 + c) * 768 + h * 32 + g * 8;
  s16x8 qfrag = *(const s16x8*)qptr;
  const short* kbase = qkv + (size_t)b * LPc * 768 + 256 + h * 32 + g * 8;
  const short* vbase_cg = vT + ((size_t)b * DDc + h * 32 + c) * LPc + g * 8;
  short* pw = &plds[wave][0];

  f32x4 o0, o1, osum;
  o0[0]=o0[1]=o0[2]=o0[3]=0.f; o1[0]=o1[1]=o1[2]=o1[3]=0.f;
  osum[0]=osum[1]=osum[2]=osum[3]=0.f;
  s16x8 ones;
#pragma unroll
  for (int j = 0; j < 8; j++) ones[j] = (short)0x3F80;  // bf16 1.0

  // prologue: tiles 0 and 1 into the two named sets
  s16x8 kA0 = *(const s16x8*)(kbase + (size_t)(0 + c) * 768);
  s16x8 kA1 = *(const s16x8*)(kbase + (size_t)(16 + c) * 768);
  s16x8 vA0 = *(const s16x8*)(vbase_cg + 0);
  s16x8 vA1 = *(const s16x8*)(vbase_cg + 16 * LPc);
  s16x8 kB0 = *(const s16x8*)(kbase + (size_t)(32 + c) * 768);
  s16x8 kB1 = *(const s16x8*)(kbase + (size_t)(48 + c) * 768);
  s16x8 vB0 = *(const s16x8*)(vbase_cg + 32);
  s16x8 vB1 = *(const s16x8*)(vbase_cg + 32 + 16 * LPc);

  for (int kt = 0; kt < 68; kt += 2) {
    flash_body(kt,     kbase, vbase_cg, pw, qfrag, ones, kA0, kA1, vA0, vA1, o0, o1, osum, g, c);
    flash_body(kt + 1, kbase, vbase_cg, pw, qfrag, ones, kB0, kB1, vB0, vB1, o0, o1, osum, g, c);
  }
#pragma unroll
  for (int i = 0; i < 4; i++) {
    int l = q0 + g * 4 + i;
    if (l < LLc) {
      float inv = 1.0f / osum[i];
      attnout[((size_t)b * LLc + l) * DDc + h * 32 + c]      = f2bf(o0[i] * inv);
      attnout[((size_t)b * LLc + l) * DDc + h * 32 + 16 + c] = f2bf(o1[i] * inv);
    }
  }
}

// ---------------- residual + layernorm (one wave per row of 256) ----------------
__global__ __launch_bounds__(256) void ln_kernel(
    const float* __restrict__ xin, const float* __restrict__ res,
    const float* __restrict__ gs, const float* __restrict__ gb,
    float* __restrict__ xout, short* __restrict__ xbout, int rows) {
  int wid = (blockIdx.x * 256 + threadIdx.x) >> 6;
  int lane = threadIdx.x & 63;
  if (wid >= rows) return;
  int dbase = lane * 4;
  float4 v = *(const float4*)(xin + (size_t)wid * DDc + dbase);
  if (res) {
    float4 r = *(const float4*)(res + (size_t)wid * DDc + dbase);
    v.x += r.x; v.y += r.y; v.z += r.z; v.w += r.w;
  }
  float s = v.x + v.y + v.z + v.w;
#pragma unroll
  for (int d = 1; d < 64; d <<= 1) s += __shfl_xor(s, d);
  float mean = s * (1.0f / 256.0f);
  float dx = v.x - mean, dy = v.y - mean, dz = v.z - mean, dw = v.w - mean;
  float sq = dx * dx + dy * dy + dz * dz + dw * dw;
#pragma unroll
  for (int d = 1; d < 64; d <<= 1) sq += __shfl_xor(sq, d);
  float rstd = rsqrtf(sq * (1.0f / 256.0f) + 1e-5f);
  float4 sg = *(const float4*)(gs + dbase);
  float4 bg = *(const float4*)(gb + dbase);
  float o0 = dx * rstd * sg.x + bg.x;
  float o1 = dy * rstd * sg.y + bg.y;
  float o2 = dz * rstd * sg.z + bg.z;
  float o3 = dw * rstd * sg.w + bg.w;
  float4 ov; ov.x = o0; ov.y = o1; ov.z = o2; ov.w = o3;
  *(float4*)(xout + (size_t)wid * DDc + dbase) = ov;
  if (xbout) {
    s16x4 pb;
    pb[0] = f2bf(o0); pb[1] = f2bf(o1); pb[2] = f2bf(o2); pb[3] = f2bf(o3);
    *(s16x4*)(xbout + (size_t)wid * DDc + dbase) = pb;
  }
}

// ---------------- launch ----------------
extern "C" void kernel_launch(void* const* d_in, const int* in_sizes, int n_in,
                              void* d_out, int out_size, void* d_ws, size_t ws_size,
                              hipStream_t stream) {
  const float* x_img = (const float*)d_in[0];
  const unsigned char* pmask = (const unsigned char*)d_in[1];
  const int* vidx = (const int*)d_in[2];
  const float* pew = (const float*)d_in[3];
  const float* peb = (const float*)d_in[4];
  const float* sp = (const float*)d_in[5];
  const float* Wqkv = (const float*)d_in[6];
  const float* bqkv = (const float*)d_in[7];
  const float* Wo = (const float*)d_in[8];
  const float* bo = (const float*)d_in[9];
  const float* ln1s = (const float*)d_in[10];
  const float* ln1b = (const float*)d_in[11];
  const float* W1 = (const float*)d_in[12];
  const float* b1 = (const float*)d_in[13];
  const float* W2 = (const float*)d_in[14];
  const float* b2 = (const float*)d_in[15];
  const float* ln2s = (const float*)d_in[16];
  const float* ln2b = (const float*)d_in[17];
  const float* nfs = (const float*)d_in[18];
  const float* nfb = (const float*)d_in[19];

  char* ws = (char*)d_ws;
  size_t o_wq = 0;
  size_t o_wo = o_wq + (size_t)NLc * 768 * DDc * 2;
  size_t o_w1 = o_wo + (size_t)NLc * DDc * DDc * 2;
  size_t o_w2 = o_w1 + (size_t)NLc * DFFc * DDc * 2;
  size_t o_pe = o_w2 + (size_t)NLc * DFFc * DDc * 2;
  size_t o_pi = o_pe + (size_t)TT * DDc * 4;
  size_t o_x  = o_pi + (size_t)MTOT * 4;
  size_t o_xb = o_x  + (size_t)MTOT * DDc * 4;
  size_t o_qk = o_xb + (size_t)MTOT * DDc * 2;
  size_t o_vt = o_qk + (size_t)BB * LPc * 768 * 2;
  size_t o_at = o_vt + (size_t)BB * DDc * LPc * 2;
  size_t o_h  = o_at + (size_t)MTOT * DDc * 2;
  size_t o_ob = o_qk;  // obuf aliases qkv region (free at that point)

  short* wqb = (short*)(ws + o_wq);
  short* wob = (short*)(ws + o_wo);
  short* w1b = (short*)(ws + o_w1);
  short* w2b = (short*)(ws + o_w2);
  float* petab = (float*)(ws + o_pe);
  int* pidx = (int*)(ws + o_pi);
  float* xbuf = (float*)(ws + o_x);
  short* xb = (short*)(ws + o_xb);
  short* qkvb = (short*)(ws + o_qk);
  short* vtb = (short*)(ws + o_vt);
  short* atb = (short*)(ws + o_at);
  short* hb = (short*)(ws + o_h);
  float* obuf = (float*)(ws + o_ob);

  const float qscale = 0.17677669529663687f * 1.4426950408889634f; // 1/sqrt(32) * log2(e)

  {
    int n;
    n = NLc * 768 * DDc;  cvt_bf16_kernel<<<(n + 255) / 256, 256, 0, stream>>>(Wqkv, wqb, n);
    n = NLc * DDc * DDc;  cvt_bf16_kernel<<<(n + 255) / 256, 256, 0, stream>>>(Wo, wob, n);
    n = NLc * DFFc * DDc; cvt_bf16_kernel<<<(n + 255) / 256, 256, 0, stream>>>(W1, w1b, n);
    n = NLc * DFFc * DDc; cvt_bf16_kernel<<<(n + 255) / 256, 256, 0, stream>>>(W2, w2b, n);
  }
  pe_kernel<<<(TT * 128 + 255) / 256, 256, 0, stream>>>(petab);
  order_kernel<<<(BB * TT + 3) / 4, 256, 0, stream>>>(pmask, vidx, pidx);
  embed_kernel<<<MTOT / 4, 256, 0, stream>>>(x_img, vidx, pidx, pew, peb, sp, petab, xbuf, xb);

  for (int i = 0; i < NLc; i++) {
    gemm_bt<GM_QKV><<<dim3(MTOT / 64, 768 / 64), 256, 0, stream>>>(
        xb, DDc, wqb + (size_t)i * 768 * DDc, DDc, bqkv + i * 768,
        qkvb, 768, DDc, vtb, qscale);
    flash_kernel<<<dim3((LLc + 63) / 64, BB * NHEADc), 256, 0, stream>>>(qkvb, vtb, atb);
    gemm_bt<GM_F32><<<dim3(MTOT / 64, DDc / 64), 256, 0, stream>>>(
        atb, DDc, wob + (size_t)i * DDc * DDc, DDc, bo + i * DDc,
        obuf, DDc, DDc, nullptr, 0.f);
    ln_kernel<<<MTOT / 4, 256, 0, stream>>>(xbuf, obuf, ln1s + i * DDc, ln1b + i * DDc, xbuf, xb, MTOT);
    gemm_bt<GM_RELU><<<dim3(MTOT / 64, DFFc / 64), 256, 0, stream>>>(
        xb, DDc, w1b + (size_t)i * DFFc * DDc, DDc, b1 + i * DFFc,
        hb, DFFc, DDc, nullptr, 0.f);
    gemm_bt<GM_F32><<<dim3(MTOT / 64, DDc / 64), 256, 0, stream>>>(
        hb, DFFc, w2b + (size_t)i * DFFc * DDc, DFFc, b2 + i * DDc,
        obuf, DDc, DFFc, nullptr, 0.f);
    ln_kernel<<<MTOT / 4, 256, 0, stream>>>(xbuf, obuf, ln2s + i * DDc, ln2b + i * DDc, xbuf, xb, MTOT);
  }
  ln_kernel<<<MTOT / 4, 256, 0, stream>>>(xbuf, nullptr, nfs, nfb, (float*)d_out, nullptr, MTOT);
}

// Round 5
// 2123.057 us; speedup vs baseline: 1.3601x; 1.2928x over previous
//
#include <hip/hip_runtime.h>
#include <hip/hip_bf16.h>
#include <math.h>

// ---- problem constants ----
#define BB 8
#define TT 90
#define HH 290
#define WWI 180
#define PSZ 10
#define NHPc 29
#define NWPc 18
#define NPc 522
#define PDc 100
#define NVc 94
#define KKc 24
#define LLc 2160
#define LPc 2176          // padded L (multiple of 32/64)
#define DDc 256
#define NHEADc 8
#define DHc 32
#define NLc 6
#define DFFc 1024
#define MTOT (BB*LLc)     // 17280

using f32x4 = __attribute__((ext_vector_type(4))) float;
using s16x8 = __attribute__((ext_vector_type(8))) short;
using s16x4 = __attribute__((ext_vector_type(4))) short;

__device__ __forceinline__ short f2bf(float f) {
  union { __hip_bfloat16 h; short s; } u;
  u.h = __float2bfloat16(f);
  return u.s;
}

// ---------------- fp32 -> bf16 weight conversion ----------------
__global__ void cvt_bf16_kernel(const float* __restrict__ src, short* __restrict__ dst, int n) {
  int i = blockIdx.x * 256 + threadIdx.x;
  if (i < n) dst[i] = f2bf(src[i]);
}

// ---------------- sinusoidal PE table (fp32) ----------------
__global__ void pe_kernel(float* __restrict__ pe) {
  int idx = blockIdx.x * 256 + threadIdx.x;
  if (idx >= TT * 128) return;
  int t = idx / 128, i = idx % 128;
  float div = expf((2.0f * i) * (-9.210340371976184f / 256.0f)); // -ln(10000)/256
  float ang = (float)t * div;
  pe[t * DDc + 2 * i]     = sinf(ang);
  pe[t * DDc + 2 * i + 1] = cosf(ang);
}

// ---------------- visible-token ordering: p_idx[b*L + t*K + j] = v ----------------
__global__ void order_kernel(const unsigned char* __restrict__ pm8,
                             const int* __restrict__ vidx, int* __restrict__ pidx) {
  int gw = (blockIdx.x * blockDim.x + threadIdx.x) >> 6;
  int lane = threadIdx.x & 63;
  if (gw >= BB * TT) return;
  size_t base = (size_t)gw * NPc;  // gw = b*TT + t
  int v0 = lane, v1 = 64 + lane;
  bool vis0 = (pm8[base + vidx[v0]] == 0);
  bool vis1 = (v1 < NVc) && (pm8[base + vidx[v1]] == 0);
  unsigned long long b0 = __ballot(vis0), b1 = __ballot(vis1);
  if (__popcll(b0) + __popcll(b1) != KKc) {   // mask was stored as int32
    const int* pm32 = (const int*)pm8;
    vis0 = (pm32[base + vidx[v0]] == 0);
    vis1 = (v1 < NVc) && (pm32[base + vidx[v1]] == 0);
    b0 = __ballot(vis0); b1 = __ballot(vis1);
  }
  int* outp = pidx + gw * KKc;   // b*L + t*K == gw*K
  unsigned long long lt = (1ull << lane) - 1ull;
  if (vis0) outp[__popcll(b0 & lt)] = v0;
  if (vis1) outp[__popcll(b0) + __popcll(b1 & lt)] = v1;
}

// ---------------- patch gather + embed + pos enc ----------------
__global__ __launch_bounds__(256) void embed_kernel(
    const float* __restrict__ ximg, const int* __restrict__ vidx,
    const int* __restrict__ pidx, const float* __restrict__ pew,
    const float* __restrict__ peb, const float* __restrict__ sp,
    const float* __restrict__ petab, float* __restrict__ x, short* __restrict__ xb) {
  __shared__ float px[4][PDc];
  int m0 = blockIdx.x * 4;
  for (int idx = threadIdx.x; idx < 4 * PDc; idx += 256) {
    int tok = idx / PDc, k = idx % PDc;
    int m = m0 + tok;
    int b = m / LLc, l = m % LLc;
    int t = l / KKc;
    int v = pidx[m];
    int np_ = vidx[v];
    int hp = np_ / NWPc, wp = np_ % NWPc;
    int r = k / PSZ, c = k % PSZ;
    px[tok][k] = ximg[(((size_t)b * TT + t) * HH + hp * PSZ + r) * WWI + wp * PSZ + c];
  }
  __syncthreads();
  int d = threadIdx.x;
  float a0 = 0.f, a1 = 0.f, a2 = 0.f, a3 = 0.f;
  const float* wrow = pew + (size_t)d * PDc;
#pragma unroll 4
  for (int k = 0; k < PDc; k++) {
    float w = wrow[k];
    a0 += w * px[0][k]; a1 += w * px[1][k]; a2 += w * px[2][k]; a3 += w * px[3][k];
  }
  float accs[4] = {a0, a1, a2, a3};
#pragma unroll
  for (int tok = 0; tok < 4; tok++) {
    int m = m0 + tok;
    int l = m % LLc; int t = l / KKc;
    int v = pidx[m];
    float val = accs[tok] + peb[d] + sp[(size_t)v * DDc + d] + petab[(size_t)t * DDc + d];
    x[(size_t)m * DDc + d] = val;
    xb[(size_t)m * DDc + d] = f2bf(val);
  }
}

// ---------------- generic bf16 MFMA GEMM: C[m,n] = sum_k A[m,k]*W[n,k] + bias[n] ----------------
#define GM_QKV 0
#define GM_F32 1
#define GM_RELU 2

template <int MODE>
__global__ __launch_bounds__(256) void gemm_bt(
    const short* __restrict__ A, int lda,
    const short* __restrict__ W, int ldw,
    const float* __restrict__ bias,
    void* __restrict__ outp, int N, int K,
    short* __restrict__ vT, float qscale) {
  __shared__ short As[64][40];
  __shared__ short Ws[64][40];
  int tid = threadIdx.x;
  int m0 = blockIdx.x * 64;
  int n0 = blockIdx.y * 64;
  int wave = tid >> 6, lane = tid & 63;
  int wr = (wave >> 1) * 32, wc = (wave & 1) * 32;
  int g = lane >> 4, c = lane & 15;
  f32x4 acc[2][2];
#pragma unroll
  for (int i = 0; i < 2; i++)
#pragma unroll
    for (int j = 0; j < 2; j++) { acc[i][j][0] = 0.f; acc[i][j][1] = 0.f; acc[i][j][2] = 0.f; acc[i][j][3] = 0.f; }
  int lrow = tid >> 2, lcg = (tid & 3) * 8;
  const short* aptr = A + (size_t)(m0 + lrow) * lda + lcg;
  const short* wptr = W + (size_t)(n0 + lrow) * ldw + lcg;
  for (int k0 = 0; k0 < K; k0 += 32) {
    *(s16x8*)&As[lrow][lcg] = *(const s16x8*)(aptr + k0);
    *(s16x8*)&Ws[lrow][lcg] = *(const s16x8*)(wptr + k0);
    __syncthreads();
    s16x8 va0 = *(const s16x8*)&As[wr + c][g * 8];
    s16x8 va1 = *(const s16x8*)&As[wr + 16 + c][g * 8];
    s16x8 vb0 = *(const s16x8*)&Ws[wc + c][g * 8];
    s16x8 vb1 = *(const s16x8*)&Ws[wc + 16 + c][g * 8];
    acc[0][0] = __builtin_amdgcn_mfma_f32_16x16x32_bf16(va0, vb0, acc[0][0], 0, 0, 0);
    acc[0][1] = __builtin_amdgcn_mfma_f32_16x16x32_bf16(va0, vb1, acc[0][1], 0, 0, 0);
    acc[1][0] = __builtin_amdgcn_mfma_f32_16x16x32_bf16(va1, vb0, acc[1][0], 0, 0, 0);
    acc[1][1] = __builtin_amdgcn_mfma_f32_16x16x32_bf16(va1, vb1, acc[1][1], 0, 0, 0);
    __syncthreads();
  }
#pragma unroll
  for (int i = 0; i < 2; i++)
#pragma unroll
    for (int j = 0; j < 2; j++) {
      int mbase = m0 + wr + i * 16 + g * 4;
      int n = n0 + wc + j * 16 + c;
      float bv = bias[n];
#pragma unroll
      for (int r = 0; r < 4; r++) {
        int m = mbase + r;
        float val = acc[i][j][r] + bv;
        if (MODE == GM_QKV) {
          int b = m / LLc, l = m % LLc;
          if (n < 512) {
            if (n < 256) val *= qscale;   // fold softmax scale * log2e into q
            ((short*)outp)[((size_t)b * LPc + l) * 768 + n] = f2bf(val);
          } else {
            // v stored transposed: vT[(b*256 + d)*LP + l]
            vT[((size_t)b * DDc + (n - 512)) * LPc + l] = f2bf(val);
          }
        } else if (MODE == GM_F32) {
          ((float*)outp)[(size_t)m * N + n] = val;
        } else {  // GM_RELU -> bf16
          ((short*)outp)[(size_t)m * N + n] = f2bf(val > 0.f ? val : 0.f);
        }
      }
    }
}

// ---------------- flash attention v4 ----------------
// r4 post-mortem: the two unrolled bodies shared one P-buffer and an asm
// memory-clobber waitcnt -> fully serialized chains. v4: (a) two P buffers so
// the unrolled bodies are independent; (b) no inline asm -- compiler-managed
// lgkmcnt (LDS aliasing is visible to it) so it can software-pipeline;
// (c) 32 q-rows per wave (2 Q-frags share each K/V tile) -> half the L2
// traffic, 10 MFMA per 4KB tile; (d) distance-2 register prefetch kept.
__device__ __forceinline__ void flash_body(
    int kt, const short* kbase, const short* vbase_cg, short* pw,
    const s16x8& qfA, const s16x8& qfB, const s16x8& ones,
    s16x8& K0, s16x8& K1, s16x8& V0, s16x8& V1,
    f32x4& o0a, f32x4& o1a, f32x4& osa,
    f32x4& o0b, f32x4& o1b, f32x4& osb, int g, int c) {
  // snapshot current tile operands
  s16x8 ck0 = K0, ck1 = K1, cv0 = V0, cv1 = V1;
  // prefetch tile kt+2 (clamped; loaded-not-used past the end)
  int nk = kt * 32 + 64;
  if (nk >= LPc) nk = 0;
  K0 = *(const s16x8*)(kbase + (size_t)(nk + c) * 768);
  K1 = *(const s16x8*)(kbase + (size_t)(nk + 16 + c) * 768);
  V0 = *(const s16x8*)(vbase_cg + nk);
  V1 = *(const s16x8*)(vbase_cg + nk + 16 * LPc);
  // QK^T for both q-frags
  f32x4 zero4; zero4[0] = zero4[1] = zero4[2] = zero4[3] = 0.f;
  f32x4 s0a = __builtin_amdgcn_mfma_f32_16x16x32_bf16(qfA, ck0, zero4, 0, 0, 0);
  f32x4 s1a = __builtin_amdgcn_mfma_f32_16x16x32_bf16(qfA, ck1, zero4, 0, 0, 0);
  f32x4 s0b = __builtin_amdgcn_mfma_f32_16x16x32_bf16(qfB, ck0, zero4, 0, 0, 0);
  f32x4 s1b = __builtin_amdgcn_mfma_f32_16x16x32_bf16(qfB, ck1, zero4, 0, 0, 0);
  if (kt == 67) {
    // keys 2160..2175 are padding (possibly poison): kill by assignment
    s1a[0] = s1a[1] = s1a[2] = s1a[3] = -1e30f;
    s1b[0] = s1b[1] = s1b[2] = s1b[3] = -1e30f;
  }
  // P = exp2(S), transposed through per-body LDS buffer (rows = 32 q, stride 40)
#pragma unroll
  for (int i = 0; i < 4; i++) {
    pw[(g * 4 + i) * 40 + c]           = f2bf(exp2f(s0a[i]));
    pw[(g * 4 + i) * 40 + 16 + c]      = f2bf(exp2f(s1a[i]));
    pw[(16 + g * 4 + i) * 40 + c]      = f2bf(exp2f(s0b[i]));
    pw[(16 + g * 4 + i) * 40 + 16 + c] = f2bf(exp2f(s1b[i]));
  }
  s16x8 pa0 = *(const s16x8*)(pw + c * 40 + g * 8);
  s16x8 pa1 = *(const s16x8*)(pw + (16 + c) * 40 + g * 8);
  o0a = __builtin_amdgcn_mfma_f32_16x16x32_bf16(pa0, cv0, o0a, 0, 0, 0);
  o1a = __builtin_amdgcn_mfma_f32_16x16x32_bf16(pa0, cv1, o1a, 0, 0, 0);
  osa = __builtin_amdgcn_mfma_f32_16x16x32_bf16(pa0, ones, osa, 0, 0, 0);
  o0b = __builtin_amdgcn_mfma_f32_16x16x32_bf16(pa1, cv0, o0b, 0, 0, 0);
  o1b = __builtin_amdgcn_mfma_f32_16x16x32_bf16(pa1, cv1, o1b, 0, 0, 0);
  osb = __builtin_amdgcn_mfma_f32_16x16x32_bf16(pa1, ones, osb, 0, 0, 0);
}

__global__ __launch_bounds__(256) void flash_kernel(
    const short* __restrict__ qkv, const short* __restrict__ vT,
    short* __restrict__ attnout) {
  __shared__ short plds[4][2][32 * 40];  // per-wave, per-pipeline-body P buffers
  int wave = threadIdx.x >> 6, lane = threadIdx.x & 63;
  int g = lane >> 4, c = lane & 15;
  int bh = blockIdx.y;
  int b = bh >> 3, h = bh & 7;
  int q0 = blockIdx.x * 128 + wave * 32;

  const short* qbase = qkv + ((size_t)b * LPc + q0 + c) * 768 + h * 32 + g * 8;
  s16x8 qfA = *(const s16x8*)qbase;                    // q rows q0..q0+15
  s16x8 qfB = *(const s16x8*)(qbase + 16 * 768);       // q rows q0+16..q0+31
  const short* kbase = qkv + (size_t)b * LPc * 768 + 256 + h * 32 + g * 8;
  const short* vbase_cg = vT + ((size_t)b * DDc + h * 32 + c) * LPc + g * 8;
  short* pw0 = &plds[wave][0][0];
  short* pw1 = &plds[wave][1][0];

  f32x4 o0a, o1a, osa, o0b, o1b, osb;
  o0a[0]=o0a[1]=o0a[2]=o0a[3]=0.f; o1a[0]=o1a[1]=o1a[2]=o1a[3]=0.f;
  osa[0]=osa[1]=osa[2]=osa[3]=0.f; o0b[0]=o0b[1]=o0b[2]=o0b[3]=0.f;
  o1b[0]=o1b[1]=o1b[2]=o1b[3]=0.f; osb[0]=osb[1]=osb[2]=osb[3]=0.f;
  s16x8 ones;
#pragma unroll
  for (int j = 0; j < 8; j++) ones[j] = (short)0x3F80;  // bf16 1.0

  // prologue: tiles 0 and 1 into the two named register sets
  s16x8 kA0 = *(const s16x8*)(kbase + (size_t)(0 + c) * 768);
  s16x8 kA1 = *(const s16x8*)(kbase + (size_t)(16 + c) * 768);
  s16x8 vA0 = *(const s16x8*)(vbase_cg + 0);
  s16x8 vA1 = *(const s16x8*)(vbase_cg + 16 * LPc);
  s16x8 kB0 = *(const s16x8*)(kbase + (size_t)(32 + c) * 768);
  s16x8 kB1 = *(const s16x8*)(kbase + (size_t)(48 + c) * 768);
  s16x8 vB0 = *(const s16x8*)(vbase_cg + 32);
  s16x8 vB1 = *(const s16x8*)(vbase_cg + 32 + 16 * LPc);

  for (int kt = 0; kt < 68; kt += 2) {
    flash_body(kt,     kbase, vbase_cg, pw0, qfA, qfB, ones,
               kA0, kA1, vA0, vA1, o0a, o1a, osa, o0b, o1b, osb, g, c);
    flash_body(kt + 1, kbase, vbase_cg, pw1, qfA, qfB, ones,
               kB0, kB1, vB0, vB1, o0a, o1a, osa, o0b, o1b, osb, g, c);
  }
#pragma unroll
  for (int i = 0; i < 4; i++) {
    int la = q0 + g * 4 + i;
    if (la < LLc) {
      float inv = 1.0f / osa[i];
      attnout[((size_t)b * LLc + la) * DDc + h * 32 + c]      = f2bf(o0a[i] * inv);
      attnout[((size_t)b * LLc + la) * DDc + h * 32 + 16 + c] = f2bf(o1a[i] * inv);
    }
    int lb = q0 + 16 + g * 4 + i;
    if (lb < LLc) {
      float inv = 1.0f / osb[i];
      attnout[((size_t)b * LLc + lb) * DDc + h * 32 + c]      = f2bf(o0b[i] * inv);
      attnout[((size_t)b * LLc + lb) * DDc + h * 32 + 16 + c] = f2bf(o1b[i] * inv);
    }
  }
}

// ---------------- residual + layernorm (one wave per row of 256) ----------------
__global__ __launch_bounds__(256) void ln_kernel(
    const float* __restrict__ xin, const float* __restrict__ res,
    const float* __restrict__ gs, const float* __restrict__ gb,
    float* __restrict__ xout, short* __restrict__ xbout, int rows) {
  int wid = (blockIdx.x * 256 + threadIdx.x) >> 6;
  int lane = threadIdx.x & 63;
  if (wid >= rows) return;
  int dbase = lane * 4;
  float4 v = *(const float4*)(xin + (size_t)wid * DDc + dbase);
  if (res) {
    float4 r = *(const float4*)(res + (size_t)wid * DDc + dbase);
    v.x += r.x; v.y += r.y; v.z += r.z; v.w += r.w;
  }
  float s = v.x + v.y + v.z + v.w;
#pragma unroll
  for (int d = 1; d < 64; d <<= 1) s += __shfl_xor(s, d);
  float mean = s * (1.0f / 256.0f);
  float dx = v.x - mean, dy = v.y - mean, dz = v.z - mean, dw = v.w - mean;
  float sq = dx * dx + dy * dy + dz * dz + dw * dw;
#pragma unroll
  for (int d = 1; d < 64; d <<= 1) sq += __shfl_xor(sq, d);
  float rstd = rsqrtf(sq * (1.0f / 256.0f) + 1e-5f);
  float4 sg = *(const float4*)(gs + dbase);
  float4 bg = *(const float4*)(gb + dbase);
  float o0 = dx * rstd * sg.x + bg.x;
  float o1 = dy * rstd * sg.y + bg.y;
  float o2 = dz * rstd * sg.z + bg.z;
  float o3 = dw * rstd * sg.w + bg.w;
  float4 ov; ov.x = o0; ov.y = o1; ov.z = o2; ov.w = o3;
  *(float4*)(xout + (size_t)wid * DDc + dbase) = ov;
  if (xbout) {
    s16x4 pb;
    pb[0] = f2bf(o0); pb[1] = f2bf(o1); pb[2] = f2bf(o2); pb[3] = f2bf(o3);
    *(s16x4*)(xbout + (size_t)wid * DDc + dbase) = pb;
  }
}

// ---------------- launch ----------------
extern "C" void kernel_launch(void* const* d_in, const int* in_sizes, int n_in,
                              void* d_out, int out_size, void* d_ws, size_t ws_size,
                              hipStream_t stream) {
  const float* x_img = (const float*)d_in[0];
  const unsigned char* pmask = (const unsigned char*)d_in[1];
  const int* vidx = (const int*)d_in[2];
  const float* pew = (const float*)d_in[3];
  const float* peb = (const float*)d_in[4];
  const float* sp = (const float*)d_in[5];
  const float* Wqkv = (const float*)d_in[6];
  const float* bqkv = (const float*)d_in[7];
  const float* Wo = (const float*)d_in[8];
  const float* bo = (const float*)d_in[9];
  const float* ln1s = (const float*)d_in[10];
  const float* ln1b = (const float*)d_in[11];
  const float* W1 = (const float*)d_in[12];
  const float* b1 = (const float*)d_in[13];
  const float* W2 = (const float*)d_in[14];
  const float* b2 = (const float*)d_in[15];
  const float* ln2s = (const float*)d_in[16];
  const float* ln2b = (const float*)d_in[17];
  const float* nfs = (const float*)d_in[18];
  const float* nfb = (const float*)d_in[19];

  char* ws = (char*)d_ws;
  size_t o_wq = 0;
  size_t o_wo = o_wq + (size_t)NLc * 768 * DDc * 2;
  size_t o_w1 = o_wo + (size_t)NLc * DDc * DDc * 2;
  size_t o_w2 = o_w1 + (size_t)NLc * DFFc * DDc * 2;
  size_t o_pe = o_w2 + (size_t)NLc * DFFc * DDc * 2;
  size_t o_pi = o_pe + (size_t)TT * DDc * 4;
  size_t o_x  = o_pi + (size_t)MTOT * 4;
  size_t o_xb = o_x  + (size_t)MTOT * DDc * 4;
  size_t o_qk = o_xb + (size_t)MTOT * DDc * 2;
  size_t o_vt = o_qk + (size_t)BB * LPc * 768 * 2;
  size_t o_at = o_vt + (size_t)BB * DDc * LPc * 2;
  size_t o_h  = o_at + (size_t)MTOT * DDc * 2;
  size_t o_ob = o_qk;  // obuf aliases qkv region (free at that point)

  short* wqb = (short*)(ws + o_wq);
  short* wob = (short*)(ws + o_wo);
  short* w1b = (short*)(ws + o_w1);
  short* w2b = (short*)(ws + o_w2);
  float* petab = (float*)(ws + o_pe);
  int* pidx = (int*)(ws + o_pi);
  float* xbuf = (float*)(ws + o_x);
  short* xb = (short*)(ws + o_xb);
  short* qkvb = (short*)(ws + o_qk);
  short* vtb = (short*)(ws + o_vt);
  short* atb = (short*)(ws + o_at);
  short* hb = (short*)(ws + o_h);
  float* obuf = (float*)(ws + o_ob);

  const float qscale = 0.17677669529663687f * 1.4426950408889634f; // 1/sqrt(32) * log2(e)

  {
    int n;
    n = NLc * 768 * DDc;  cvt_bf16_kernel<<<(n + 255) / 256, 256, 0, stream>>>(Wqkv, wqb, n);
    n = NLc * DDc * DDc;  cvt_bf16_kernel<<<(n + 255) / 256, 256, 0, stream>>>(Wo, wob, n);
    n = NLc * DFFc * DDc; cvt_bf16_kernel<<<(n + 255) / 256, 256, 0, stream>>>(W1, w1b, n);
    n = NLc * DFFc * DDc; cvt_bf16_kernel<<<(n + 255) / 256, 256, 0, stream>>>(W2, w2b, n);
  }
  pe_kernel<<<(TT * 128 + 255) / 256, 256, 0, stream>>>(petab);
  order_kernel<<<(BB * TT + 3) / 4, 256, 0, stream>>>(pmask, vidx, pidx);
  embed_kernel<<<MTOT / 4, 256, 0, stream>>>(x_img, vidx, pidx, pew, peb, sp, petab, xbuf, xb);

  for (int i = 0; i < NLc; i++) {
    gemm_bt<GM_QKV><<<dim3(MTOT / 64, 768 / 64), 256, 0, stream>>>(
        xb, DDc, wqb + (size_t)i * 768 * DDc, DDc, bqkv + i * 768,
        qkvb, 768, DDc, vtb, qscale);
    flash_kernel<<<dim3(LPc / 128, BB * NHEADc), 256, 0, stream>>>(qkvb, vtb, atb);
    gemm_bt<GM_F32><<<dim3(MTOT / 64, DDc / 64), 256, 0, stream>>>(
        atb, DDc, wob + (size_t)i * DDc * DDc, DDc, bo + i * DDc,
        obuf, DDc, DDc, nullptr, 0.f);
    ln_kernel<<<MTOT / 4, 256, 0, stream>>>(xbuf, obuf, ln1s + i * DDc, ln1b + i * DDc, xbuf, xb, MTOT);
    gemm_bt<GM_RELU><<<dim3(MTOT / 64, DFFc / 64), 256, 0, stream>>>(
        xb, DDc, w1b + (size_t)i * DFFc * DDc, DDc, b1 + i * DFFc,
        hb, DFFc, DDc, nullptr, 0.f);
    gemm_bt<GM_F32><<<dim3(MTOT / 64, DDc / 64), 256, 0, stream>>>(
        hb, DFFc, w2b + (size_t)i * DFFc * DDc, DFFc, b2 + i * DDc,
        obuf, DDc, DFFc, nullptr, 0.f);
    ln_kernel<<<MTOT / 4, 256, 0, stream>>>(xbuf, obuf, ln2s + i * DDc, ln2b + i * DDc, xbuf, xb, MTOT);
  }
  ln_kernel<<<MTOT / 4, 256, 0, stream>>>(xbuf, nullptr, nfs, nfb, (float*)d_out, nullptr, MTOT);
}

// Round 6
// 2107.973 us; speedup vs baseline: 1.3698x; 1.0072x over previous
//
#include <hip/hip_runtime.h>
#include <hip/hip_bf16.h>
#include <math.h>

// ---- problem constants ----
#define BB 8
#define TT 90
#define HH 290
#define WWI 180
#define PSZ 10
#define NHPc 29
#define NWPc 18
#define NPc 522
#define PDc 100
#define NVc 94
#define KKc 24
#define LLc 2160
#define LPc 2176          // padded L (multiple of 32/64)
#define DDc 256
#define NHEADc 8
#define DHc 32
#define NLc 6
#define DFFc 1024
#define MTOT (BB*LLc)     // 17280

using f32x4 = __attribute__((ext_vector_type(4))) float;
using s16x8 = __attribute__((ext_vector_type(8))) short;
using s16x4 = __attribute__((ext_vector_type(4))) short;

__device__ __forceinline__ short f2bf(float f) {
  union { __hip_bfloat16 h; short s; } u;
  u.h = __float2bfloat16(f);
  return u.s;
}

// async global->LDS, 16B per lane per instr; LDS dest is wave-uniform base + lane*16
__device__ __forceinline__ void gload16(const short* g, short* l) {
  __builtin_amdgcn_global_load_lds(
      (const __attribute__((address_space(1))) void*)g,
      (__attribute__((address_space(3))) void*)l, 16, 0, 0);
}

// ---------------- fp32 -> bf16 weight conversion ----------------
__global__ void cvt_bf16_kernel(const float* __restrict__ src, short* __restrict__ dst, int n) {
  int i = blockIdx.x * 256 + threadIdx.x;
  if (i < n) dst[i] = f2bf(src[i]);
}

// ---------------- sinusoidal PE table (fp32) ----------------
__global__ void pe_kernel(float* __restrict__ pe) {
  int idx = blockIdx.x * 256 + threadIdx.x;
  if (idx >= TT * 128) return;
  int t = idx / 128, i = idx % 128;
  float div = expf((2.0f * i) * (-9.210340371976184f / 256.0f)); // -ln(10000)/256
  float ang = (float)t * div;
  pe[t * DDc + 2 * i]     = sinf(ang);
  pe[t * DDc + 2 * i + 1] = cosf(ang);
}

// ---------------- visible-token ordering: p_idx[b*L + t*K + j] = v ----------------
__global__ void order_kernel(const unsigned char* __restrict__ pm8,
                             const int* __restrict__ vidx, int* __restrict__ pidx) {
  int gw = (blockIdx.x * blockDim.x + threadIdx.x) >> 6;
  int lane = threadIdx.x & 63;
  if (gw >= BB * TT) return;
  size_t base = (size_t)gw * NPc;  // gw = b*TT + t
  int v0 = lane, v1 = 64 + lane;
  bool vis0 = (pm8[base + vidx[v0]] == 0);
  bool vis1 = (v1 < NVc) && (pm8[base + vidx[v1]] == 0);
  unsigned long long b0 = __ballot(vis0), b1 = __ballot(vis1);
  if (__popcll(b0) + __popcll(b1) != KKc) {   // mask was stored as int32
    const int* pm32 = (const int*)pm8;
    vis0 = (pm32[base + vidx[v0]] == 0);
    vis1 = (v1 < NVc) && (pm32[base + vidx[v1]] == 0);
    b0 = __ballot(vis0); b1 = __ballot(vis1);
  }
  int* outp = pidx + gw * KKc;   // b*L + t*K == gw*K
  unsigned long long lt = (1ull << lane) - 1ull;
  if (vis0) outp[__popcll(b0 & lt)] = v0;
  if (vis1) outp[__popcll(b0) + __popcll(b1 & lt)] = v1;
}

// ---------------- patch gather + embed + pos enc ----------------
__global__ __launch_bounds__(256) void embed_kernel(
    const float* __restrict__ ximg, const int* __restrict__ vidx,
    const int* __restrict__ pidx, const float* __restrict__ pew,
    const float* __restrict__ peb, const float* __restrict__ sp,
    const float* __restrict__ petab, float* __restrict__ x, short* __restrict__ xb) {
  __shared__ float px[4][PDc];
  int m0 = blockIdx.x * 4;
  for (int idx = threadIdx.x; idx < 4 * PDc; idx += 256) {
    int tok = idx / PDc, k = idx % PDc;
    int m = m0 + tok;
    int b = m / LLc, l = m % LLc;
    int t = l / KKc;
    int v = pidx[m];
    int np_ = vidx[v];
    int hp = np_ / NWPc, wp = np_ % NWPc;
    int r = k / PSZ, c = k % PSZ;
    px[tok][k] = ximg[(((size_t)b * TT + t) * HH + hp * PSZ + r) * WWI + wp * PSZ + c];
  }
  __syncthreads();
  int d = threadIdx.x;
  float a0 = 0.f, a1 = 0.f, a2 = 0.f, a3 = 0.f;
  const float* wrow = pew + (size_t)d * PDc;
#pragma unroll 4
  for (int k = 0; k < PDc; k++) {
    float w = wrow[k];
    a0 += w * px[0][k]; a1 += w * px[1][k]; a2 += w * px[2][k]; a3 += w * px[3][k];
  }
  float accs[4] = {a0, a1, a2, a3};
#pragma unroll
  for (int tok = 0; tok < 4; tok++) {
    int m = m0 + tok;
    int l = m % LLc; int t = l / KKc;
    int v = pidx[m];
    float val = accs[tok] + peb[d] + sp[(size_t)v * DDc + d] + petab[(size_t)t * DDc + d];
    x[(size_t)m * DDc + d] = val;
    xb[(size_t)m * DDc + d] = f2bf(val);
  }
}

// ---------------- 128xBN MFMA GEMM (m97 structure): C[m,n] = A[m,:].W[n,:] + bias ----------------
// 4 waves (2x2), wave quadrant 64 x BN/2; BK=32; global_load_lds width-16 staging;
// 2 barriers per K-step; 16 (BN=128) or 8 (BN=64) MFMA per wave per step.
#define GM_QKV 0
#define GM_F32 1
#define GM_RELU 2

template <int MODE, int BN>
__global__ __launch_bounds__(256) void gemm128(
    const short* __restrict__ A, int lda,
    const short* __restrict__ W, int ldw,
    const float* __restrict__ bias,
    void* __restrict__ outp, int N, int K,
    short* __restrict__ vT, float qscale) {
  constexpr int WN = BN / 2;        // wave cols
  constexpr int NF = WN / 16;       // B frags per wave (4 or 2)
  __shared__ short As[128 * 32];
  __shared__ short Bs[BN * 32];
  int tid = threadIdx.x;
  int wave = tid >> 6, lane = tid & 63;
  int g = lane >> 4, c = lane & 15;
  int m0 = blockIdx.x * 128, n0 = blockIdx.y * BN;
  int wr = (wave >> 1) * 64, wc = (wave & 1) * WN;

  int lr = lane >> 2;               // 0..15
  int scol = (lane & 3) * 8;        // k offset within BK
  const short* asrc = A + (size_t)(m0 + wave * 32 + lr) * lda + scol;
  short* aldst = As + wave * 1024;  // lane*8 shorts appended by HW
  const short* wsrc;
  short* bldst;
  if (BN == 128) {
    wsrc = W + (size_t)(n0 + wave * 32 + lr) * ldw + scol;
    bldst = Bs + wave * 1024;
  } else {
    wsrc = W + (size_t)(n0 + wave * 16 + lr) * ldw + scol;
    bldst = Bs + wave * 512;
  }

  f32x4 acc[4][NF];
#pragma unroll
  for (int i = 0; i < 4; i++)
#pragma unroll
    for (int j = 0; j < NF; j++) { acc[i][j][0]=0.f; acc[i][j][1]=0.f; acc[i][j][2]=0.f; acc[i][j][3]=0.f; }

  for (int k0 = 0; k0 < K; k0 += 32) {
    gload16(asrc + k0, aldst);
    gload16(asrc + 16 * lda + k0, aldst + 512);
    gload16(wsrc + k0, bldst);
    if (BN == 128) gload16(wsrc + 16 * ldw + k0, bldst + 512);
    __syncthreads();   // compiler drains vmcnt before barrier
    s16x8 af[4], bf[NF];
#pragma unroll
    for (int f = 0; f < 4; f++) af[f] = *(const s16x8*)&As[(wr + f * 16 + c) * 32 + g * 8];
#pragma unroll
    for (int f = 0; f < NF; f++) bf[f] = *(const s16x8*)&Bs[(wc + f * 16 + c) * 32 + g * 8];
#pragma unroll
    for (int i = 0; i < 4; i++)
#pragma unroll
      for (int j = 0; j < NF; j++)
        acc[i][j] = __builtin_amdgcn_mfma_f32_16x16x32_bf16(af[i], bf[j], acc[i][j], 0, 0, 0);
    __syncthreads();   // all reads done before next stage overwrites
  }

#pragma unroll
  for (int i = 0; i < 4; i++) {
#pragma unroll
    for (int j = 0; j < NF; j++) {
      int n = n0 + wc + j * 16 + c;
      float bv = bias[n];
      int mbase = m0 + wr + i * 16 + g * 4;
#pragma unroll
      for (int r = 0; r < 4; r++) {
        int m = mbase + r;
        float val = acc[i][j][r] + bv;
        if (MODE == GM_QKV) {
          int b = m / LLc, l = m % LLc;
          if (n < 512) {
            if (n < 256) val *= qscale;   // fold softmax scale * log2e into q
            ((short*)outp)[((size_t)b * LPc + l) * 768 + n] = f2bf(val);
          } else {
            // v stored transposed: vT[(b*256 + d)*LP + l]
            vT[((size_t)b * DDc + (n - 512)) * LPc + l] = f2bf(val);
          }
        } else if (MODE == GM_F32) {
          ((float*)outp)[(size_t)m * N + n] = val;
        } else {  // GM_RELU -> bf16
          ((short*)outp)[(size_t)m * N + n] = f2bf(val > 0.f ? val : 0.f);
        }
      }
    }
  }
}

// ---------------- flash attention v4 (unchanged from r5) ----------------
__device__ __forceinline__ void flash_body(
    int kt, const short* kbase, const short* vbase_cg, short* pw,
    const s16x8& qfA, const s16x8& qfB, const s16x8& ones,
    s16x8& K0, s16x8& K1, s16x8& V0, s16x8& V1,
    f32x4& o0a, f32x4& o1a, f32x4& osa,
    f32x4& o0b, f32x4& o1b, f32x4& osb, int g, int c) {
  s16x8 ck0 = K0, ck1 = K1, cv0 = V0, cv1 = V1;
  int nk = kt * 32 + 64;
  if (nk >= LPc) nk = 0;
  K0 = *(const s16x8*)(kbase + (size_t)(nk + c) * 768);
  K1 = *(const s16x8*)(kbase + (size_t)(nk + 16 + c) * 768);
  V0 = *(const s16x8*)(vbase_cg + nk);
  V1 = *(const s16x8*)(vbase_cg + nk + 16 * LPc);
  f32x4 zero4; zero4[0] = zero4[1] = zero4[2] = zero4[3] = 0.f;
  f32x4 s0a = __builtin_amdgcn_mfma_f32_16x16x32_bf16(qfA, ck0, zero4, 0, 0, 0);
  f32x4 s1a = __builtin_amdgcn_mfma_f32_16x16x32_bf16(qfA, ck1, zero4, 0, 0, 0);
  f32x4 s0b = __builtin_amdgcn_mfma_f32_16x16x32_bf16(qfB, ck0, zero4, 0, 0, 0);
  f32x4 s1b = __builtin_amdgcn_mfma_f32_16x16x32_bf16(qfB, ck1, zero4, 0, 0, 0);
  if (kt == 67) {
    s1a[0] = s1a[1] = s1a[2] = s1a[3] = -1e30f;
    s1b[0] = s1b[1] = s1b[2] = s1b[3] = -1e30f;
  }
#pragma unroll
  for (int i = 0; i < 4; i++) {
    pw[(g * 4 + i) * 40 + c]           = f2bf(exp2f(s0a[i]));
    pw[(g * 4 + i) * 40 + 16 + c]      = f2bf(exp2f(s1a[i]));
    pw[(16 + g * 4 + i) * 40 + c]      = f2bf(exp2f(s0b[i]));
    pw[(16 + g * 4 + i) * 40 + 16 + c] = f2bf(exp2f(s1b[i]));
  }
  s16x8 pa0 = *(const s16x8*)(pw + c * 40 + g * 8);
  s16x8 pa1 = *(const s16x8*)(pw + (16 + c) * 40 + g * 8);
  o0a = __builtin_amdgcn_mfma_f32_16x16x32_bf16(pa0, cv0, o0a, 0, 0, 0);
  o1a = __builtin_amdgcn_mfma_f32_16x16x32_bf16(pa0, cv1, o1a, 0, 0, 0);
  osa = __builtin_amdgcn_mfma_f32_16x16x32_bf16(pa0, ones, osa, 0, 0, 0);
  o0b = __builtin_amdgcn_mfma_f32_16x16x32_bf16(pa1, cv0, o0b, 0, 0, 0);
  o1b = __builtin_amdgcn_mfma_f32_16x16x32_bf16(pa1, cv1, o1b, 0, 0, 0);
  osb = __builtin_amdgcn_mfma_f32_16x16x32_bf16(pa1, ones, osb, 0, 0, 0);
}

__global__ __launch_bounds__(256) void flash_kernel(
    const short* __restrict__ qkv, const short* __restrict__ vT,
    short* __restrict__ attnout) {
  __shared__ short plds[4][2][32 * 40];  // per-wave, per-pipeline-body P buffers
  int wave = threadIdx.x >> 6, lane = threadIdx.x & 63;
  int g = lane >> 4, c = lane & 15;
  int bh = blockIdx.y;
  int b = bh >> 3, h = bh & 7;
  int q0 = blockIdx.x * 128 + wave * 32;

  const short* qbase = qkv + ((size_t)b * LPc + q0 + c) * 768 + h * 32 + g * 8;
  s16x8 qfA = *(const s16x8*)qbase;                    // q rows q0..q0+15
  s16x8 qfB = *(const s16x8*)(qbase + 16 * 768);       // q rows q0+16..q0+31
  const short* kbase = qkv + (size_t)b * LPc * 768 + 256 + h * 32 + g * 8;
  const short* vbase_cg = vT + ((size_t)b * DDc + h * 32 + c) * LPc + g * 8;
  short* pw0 = &plds[wave][0][0];
  short* pw1 = &plds[wave][1][0];

  f32x4 o0a, o1a, osa, o0b, o1b, osb;
  o0a[0]=o0a[1]=o0a[2]=o0a[3]=0.f; o1a[0]=o1a[1]=o1a[2]=o1a[3]=0.f;
  osa[0]=osa[1]=osa[2]=osa[3]=0.f; o0b[0]=o0b[1]=o0b[2]=o0b[3]=0.f;
  o1b[0]=o1b[1]=o1b[2]=o1b[3]=0.f; osb[0]=osb[1]=osb[2]=osb[3]=0.f;
  s16x8 ones;
#pragma unroll
  for (int j = 0; j < 8; j++) ones[j] = (short)0x3F80;  // bf16 1.0

  s16x8 kA0 = *(const s16x8*)(kbase + (size_t)(0 + c) * 768);
  s16x8 kA1 = *(const s16x8*)(kbase + (size_t)(16 + c) * 768);
  s16x8 vA0 = *(const s16x8*)(vbase_cg + 0);
  s16x8 vA1 = *(const s16x8*)(vbase_cg + 16 * LPc);
  s16x8 kB0 = *(const s16x8*)(kbase + (size_t)(32 + c) * 768);
  s16x8 kB1 = *(const s16x8*)(kbase + (size_t)(48 + c) * 768);
  s16x8 vB0 = *(const s16x8*)(vbase_cg + 32);
  s16x8 vB1 = *(const s16x8*)(vbase_cg + 32 + 16 * LPc);

  for (int kt = 0; kt < 68; kt += 2) {
    flash_body(kt,     kbase, vbase_cg, pw0, qfA, qfB, ones,
               kA0, kA1, vA0, vA1, o0a, o1a, osa, o0b, o1b, osb, g, c);
    flash_body(kt + 1, kbase, vbase_cg, pw1, qfA, qfB, ones,
               kB0, kB1, vB0, vB1, o0a, o1a, osa, o0b, o1b, osb, g, c);
  }
#pragma unroll
  for (int i = 0; i < 4; i++) {
    int la = q0 + g * 4 + i;
    if (la < LLc) {
      float inv = 1.0f / osa[i];
      attnout[((size_t)b * LLc + la) * DDc + h * 32 + c]      = f2bf(o0a[i] * inv);
      attnout[((size_t)b * LLc + la) * DDc + h * 32 + 16 + c] = f2bf(o1a[i] * inv);
    }
    int lb = q0 + 16 + g * 4 + i;
    if (lb < LLc) {
      float inv = 1.0f / osb[i];
      attnout[((size_t)b * LLc + lb) * DDc + h * 32 + c]      = f2bf(o0b[i] * inv);
      attnout[((size_t)b * LLc + lb) * DDc + h * 32 + 16 + c] = f2bf(o1b[i] * inv);
    }
  }
}

// ---------------- residual + layernorm (one wave per row of 256) ----------------
__global__ __launch_bounds__(256) void ln_kernel(
    const float* __restrict__ xin, const float* __restrict__ res,
    const float* __restrict__ gs, const float* __restrict__ gb,
    float* __restrict__ xout, short* __restrict__ xbout, int rows) {
  int wid = (blockIdx.x * 256 + threadIdx.x) >> 6;
  int lane = threadIdx.x & 63;
  if (wid >= rows) return;
  int dbase = lane * 4;
  float4 v = *(const float4*)(xin + (size_t)wid * DDc + dbase);
  if (res) {
    float4 r = *(const float4*)(res + (size_t)wid * DDc + dbase);
    v.x += r.x; v.y += r.y; v.z += r.z; v.w += r.w;
  }
  float s = v.x + v.y + v.z + v.w;
#pragma unroll
  for (int d = 1; d < 64; d <<= 1) s += __shfl_xor(s, d);
  float mean = s * (1.0f / 256.0f);
  float dx = v.x - mean, dy = v.y - mean, dz = v.z - mean, dw = v.w - mean;
  float sq = dx * dx + dy * dy + dz * dz + dw * dw;
#pragma unroll
  for (int d = 1; d < 64; d <<= 1) sq += __shfl_xor(sq, d);
  float rstd = rsqrtf(sq * (1.0f / 256.0f) + 1e-5f);
  float4 sg = *(const float4*)(gs + dbase);
  float4 bg = *(const float4*)(gb + dbase);
  float o0 = dx * rstd * sg.x + bg.x;
  float o1 = dy * rstd * sg.y + bg.y;
  float o2 = dz * rstd * sg.z + bg.z;
  float o3 = dw * rstd * sg.w + bg.w;
  float4 ov; ov.x = o0; ov.y = o1; ov.z = o2; ov.w = o3;
  *(float4*)(xout + (size_t)wid * DDc + dbase) = ov;
  if (xbout) {
    s16x4 pb;
    pb[0] = f2bf(o0); pb[1] = f2bf(o1); pb[2] = f2bf(o2); pb[3] = f2bf(o3);
    *(s16x4*)(xbout + (size_t)wid * DDc + dbase) = pb;
  }
}

// ---------------- launch ----------------
extern "C" void kernel_launch(void* const* d_in, const int* in_sizes, int n_in,
                              void* d_out, int out_size, void* d_ws, size_t ws_size,
                              hipStream_t stream) {
  const float* x_img = (const float*)d_in[0];
  const unsigned char* pmask = (const unsigned char*)d_in[1];
  const int* vidx = (const int*)d_in[2];
  const float* pew = (const float*)d_in[3];
  const float* peb = (const float*)d_in[4];
  const float* sp = (const float*)d_in[5];
  const float* Wqkv = (const float*)d_in[6];
  const float* bqkv = (const float*)d_in[7];
  const float* Wo = (const float*)d_in[8];
  const float* bo = (const float*)d_in[9];
  const float* ln1s = (const float*)d_in[10];
  const float* ln1b = (const float*)d_in[11];
  const float* W1 = (const float*)d_in[12];
  const float* b1 = (const float*)d_in[13];
  const float* W2 = (const float*)d_in[14];
  const float* b2 = (const float*)d_in[15];
  const float* ln2s = (const float*)d_in[16];
  const float* ln2b = (const float*)d_in[17];
  const float* nfs = (const float*)d_in[18];
  const float* nfb = (const float*)d_in[19];

  char* ws = (char*)d_ws;
  size_t o_wq = 0;
  size_t o_wo = o_wq + (size_t)NLc * 768 * DDc * 2;
  size_t o_w1 = o_wo + (size_t)NLc * DDc * DDc * 2;
  size_t o_w2 = o_w1 + (size_t)NLc * DFFc * DDc * 2;
  size_t o_pe = o_w2 + (size_t)NLc * DFFc * DDc * 2;
  size_t o_pi = o_pe + (size_t)TT * DDc * 4;
  size_t o_x  = o_pi + (size_t)MTOT * 4;
  size_t o_xb = o_x  + (size_t)MTOT * DDc * 4;
  size_t o_qk = o_xb + (size_t)MTOT * DDc * 2;
  size_t o_vt = o_qk + (size_t)BB * LPc * 768 * 2;
  size_t o_at = o_vt + (size_t)BB * DDc * LPc * 2;
  size_t o_h  = o_at + (size_t)MTOT * DDc * 2;
  size_t o_ob = o_qk;  // obuf aliases qkv region (free at that point)

  short* wqb = (short*)(ws + o_wq);
  short* wob = (short*)(ws + o_wo);
  short* w1b = (short*)(ws + o_w1);
  short* w2b = (short*)(ws + o_w2);
  float* petab = (float*)(ws + o_pe);
  int* pidx = (int*)(ws + o_pi);
  float* xbuf = (float*)(ws + o_x);
  short* xb = (short*)(ws + o_xb);
  short* qkvb = (short*)(ws + o_qk);
  short* vtb = (short*)(ws + o_vt);
  short* atb = (short*)(ws + o_at);
  short* hb = (short*)(ws + o_h);
  float* obuf = (float*)(ws + o_ob);

  const float qscale = 0.17677669529663687f * 1.4426950408889634f; // 1/sqrt(32) * log2(e)

  {
    int n;
    n = NLc * 768 * DDc;  cvt_bf16_kernel<<<(n + 255) / 256, 256, 0, stream>>>(Wqkv, wqb, n);
    n = NLc * DDc * DDc;  cvt_bf16_kernel<<<(n + 255) / 256, 256, 0, stream>>>(Wo, wob, n);
    n = NLc * DFFc * DDc; cvt_bf16_kernel<<<(n + 255) / 256, 256, 0, stream>>>(W1, w1b, n);
    n = NLc * DFFc * DDc; cvt_bf16_kernel<<<(n + 255) / 256, 256, 0, stream>>>(W2, w2b, n);
  }
  pe_kernel<<<(TT * 128 + 255) / 256, 256, 0, stream>>>(petab);
  order_kernel<<<(BB * TT + 3) / 4, 256, 0, stream>>>(pmask, vidx, pidx);
  embed_kernel<<<MTOT / 4, 256, 0, stream>>>(x_img, vidx, pidx, pew, peb, sp, petab, xbuf, xb);

  for (int i = 0; i < NLc; i++) {
    gemm128<GM_QKV, 128><<<dim3(MTOT / 128, 768 / 128), 256, 0, stream>>>(
        xb, DDc, wqb + (size_t)i * 768 * DDc, DDc, bqkv + i * 768,
        qkvb, 768, DDc, vtb, qscale);
    flash_kernel<<<dim3(LPc / 128, BB * NHEADc), 256, 0, stream>>>(qkvb, vtb, atb);
    gemm128<GM_F32, 64><<<dim3(MTOT / 128, DDc / 64), 256, 0, stream>>>(
        atb, DDc, wob + (size_t)i * DDc * DDc, DDc, bo + i * DDc,
        obuf, DDc, DDc, nullptr, 0.f);
    ln_kernel<<<MTOT / 4, 256, 0, stream>>>(xbuf, obuf, ln1s + i * DDc, ln1b + i * DDc, xbuf, xb, MTOT);
    gemm128<GM_RELU, 128><<<dim3(MTOT / 128, DFFc / 128), 256, 0, stream>>>(
        xb, DDc, w1b + (size_t)i * DFFc * DDc, DDc, b1 + i * DFFc,
        hb, DFFc, DDc, nullptr, 0.f);
    gemm128<GM_F32, 64><<<dim3(MTOT / 128, DDc / 64), 256, 0, stream>>>(
        hb, DFFc, w2b + (size_t)i * DFFc * DDc, DFFc, b2 + i * DDc,
        obuf, DDc, DFFc, nullptr, 0.f);
    ln_kernel<<<MTOT / 4, 256, 0, stream>>>(xbuf, obuf, ln2s + i * DDc, ln2b + i * DDc, xbuf, xb, MTOT);
  }
  ln_kernel<<<MTOT / 4, 256, 0, stream>>>(xbuf, nullptr, nfs, nfb, (float*)d_out, nullptr, MTOT);
}